// Round 1
// 363.333 us; speedup vs baseline: 1.1898x; 1.1898x over previous
//
#include <hip/hip_runtime.h>
#include <stdint.h>
#include <stddef.h>

typedef __attribute__((ext_vector_type(8))) short short8;
typedef __attribute__((ext_vector_type(4))) float f32x4;

#define N_IMG 32
#define C_IN  256
#define HH    64
#define WW    64
#define O_OUT 256
#define HP    66
#define WP    66

#define QX_ELEMS (N_IMG*HP*WP*C_IN)      // 35,684,352
#define QX_BYTES ((size_t)QX_ELEMS*2)    // 71,368,704
#define QW_ELEMS (9*O_OUT*C_IN)          // 589,824

// ---------- quantization helpers (match jnp reference bit-for-bit) ----------

// nearest E2M1 magnitude; ties round up (jnp.digitize right=False: a==mid -> upper)
__device__ __forceinline__ float e2m1_mag(float a) {
    return a < 0.25f ? 0.0f
         : a < 0.75f ? 0.5f
         : a < 1.25f ? 1.0f
         : a < 1.75f ? 1.5f
         : a < 2.5f  ? 2.0f
         : a < 3.5f  ? 3.0f
         : a < 5.0f  ? 4.0f : 6.0f;
}

// scale = 2^ceil(log2(max(amax,1e-30)/6)), or 1.0 if amax==0; also exact 1/scale.
__device__ __forceinline__ void blk_scale2(float amax, float& s, float& inv) {
    float ac = fmaxf(amax, 1e-30f);
    int e;
    float m = frexpf(ac, &e);
    int ex = (m > 0.75f) ? (e - 2) : (e - 3);
    if (amax > 0.0f) { s = ldexpf(1.0f, ex); inv = ldexpf(1.0f, -ex); }
    else             { s = 1.0f; inv = 1.0f; }
}

// E2M1-grid * pow2 -> 1 mantissa bit -> exact in bf16 (truncate == round)
__device__ __forceinline__ unsigned short to_bf16_bits(float v) {
    union { float f; unsigned int u; } cv; cv.f = v;
    return (unsigned short)(cv.u >> 16);
}

// ---------- halo zero: only the 4.3 MB border of qx (replaces 71 MB memset) ----------
// Region A: h in {0,65}, all (w,c): 32*2*2112 uint4 = 135168
// Region B: h in 1..64, w in {0,65}: 32*4096 uint4 = 131072 ; total 266240 = 1040*256
__global__ __launch_bounds__(256) void halo_zero_kernel(unsigned short* __restrict__ qx) {
    int id = blockIdx.x * 256 + threadIdx.x;
    size_t off;
    if (id < 135168) {
        int n = id / 4224, r = id % 4224;
        int h = (r / 2112) * 65;
        int k = r % 2112;
        off = (((size_t)(n*HP + h)) * WP) * C_IN + (size_t)k * 8;
    } else {
        int j = id - 135168;
        int n = j >> 12, r = j & 4095;
        int h = 1 + (r >> 6);
        int w = ((r >> 5) & 1) * 65;
        int k = r & 31;
        off = (((size_t)(n*HP + h)) * WP + w) * C_IN + (size_t)k * 8;
    }
    uint4 z; z.x = z.y = z.z = z.w = 0u;
    *(uint4*)(qx + off) = z;
}

// ---------- x: fp32 NCHW -> exact-bf16 NHWC(+halo) ----------
__global__ __launch_bounds__(256) void quant_x_kernel(const float* __restrict__ x,
                                                      unsigned short* __restrict__ qx) {
    __shared__ float xf[64][65];     // [c_local][w], pad 1 -> transpose reads 2-way
    __shared__ float sarr[4][65];    // [wb][c_local] scale
    __shared__ float iarr[4][65];    // [wb][c_local] 1/scale (exact pow2)

    const int bid = blockIdx.x;
    const int n  = bid >> 8;
    const int h  = (bid >> 2) & 63;
    const int cb = bid & 3;
    const int t  = threadIdx.x;

    {
        const int rb = t >> 4;            // 0..15
        const int w4 = (t & 15) * 4;
        const float* src = x + (((size_t)(n*C_IN + cb*64)) * HH + h) * WW;
#pragma unroll
        for (int it = 0; it < 4; ++it) {
            int r = it * 16 + rb;
            float4 g = *(const float4*)(src + (size_t)r * (HH*WW) + w4);
            xf[r][w4+0] = g.x; xf[r][w4+1] = g.y; xf[r][w4+2] = g.z; xf[r][w4+3] = g.w;
        }
    }
    __syncthreads();

    {
        const int c = t >> 2, wb = t & 3;
        float amax = 0.f;
#pragma unroll
        for (int j = 0; j < 16; ++j) amax = fmaxf(amax, fabsf(xf[c][wb*16 + j]));
        float s, inv;
        blk_scale2(amax, s, inv);
        sarr[wb][c] = s;
        iarr[wb][c] = inv;
    }
    __syncthreads();

    {
        const int w = t >> 2, cg = (t & 3) * 16, wb = w >> 4;
        unsigned short outv[16];
#pragma unroll
        for (int i = 0; i < 16; ++i) {
            int c = cg + i;
            float v = xf[c][w];
            float q = copysignf(e2m1_mag(fabsf(v) * iarr[wb][c]) * sarr[wb][c], v);
            outv[i] = to_bf16_bits(q);
        }
        unsigned short* dst = qx + (((size_t)(n*HP + h + 1)) * WP + (w + 1)) * C_IN + cb*64 + cg;
        *(uint4*)(dst)     = *(const uint4*)&outv[0];
        *(uint4*)(dst + 8) = *(const uint4*)&outv[8];
    }
}

// ---------- w: fp32 OIHW -> exact-bf16 [kpos][O][C], one block per o ----------
__global__ __launch_bounds__(256) void quant_w_kernel(const float* __restrict__ w,
                                                      unsigned short* __restrict__ qw) {
    __shared__ unsigned short lq[2304];   // one o-row, flat (ci*9 + p) order
    const int o = blockIdx.x;
    const int t = threadIdx.x;
    const float* src = w + (size_t)o * 2304;
    if (t < 144) {                        // 144 quant blocks of 16 per o
        float v[16];
#pragma unroll
        for (int j = 0; j < 4; ++j) {
            float4 f = ((const float4*)(src + t*16))[j];
            v[j*4+0]=f.x; v[j*4+1]=f.y; v[j*4+2]=f.z; v[j*4+3]=f.w;
        }
        float amax = 0.f;
#pragma unroll
        for (int j = 0; j < 16; ++j) amax = fmaxf(amax, fabsf(v[j]));
        float s, inv;
        blk_scale2(amax, s, inv);
#pragma unroll
        for (int j = 0; j < 16; ++j)
            lq[t*16 + j] = to_bf16_bits(copysignf(e2m1_mag(fabsf(v[j]) * inv) * s, v[j]));
    }
    __syncthreads();
#pragma unroll
    for (int p = 0; p < 9; ++p)
        qw[((size_t)(p*O_OUT + o)) * C_IN + t] = lq[t*9 + p];
}

// ---------- conv: implicit GEMM, 256x256 tile, BK=64, 8-phase counted-vmcnt ----------
// A = weights [O=256][K], B = pixels [256][K]; K = 9 taps x 256 ch = 36 K-tiles of 64.
// 8 waves (2M x 4N): wave owns 128(o) x 64(pix). LDS 128 KiB = 2 dbuf x (A 32K + B 32K).
// T2: XOR swizzle byte ^= (row&7)<<4 on 128-B rows; global_load_lds writes linearly so
// the *global* source address is inverse-swizzled and ds_reads apply the same XOR.
// T3+T4: per K-tile 4 phases, each {ds_read quadrant; issue 2 glds for tile t+1;
// barrier; lgkmcnt(0); setprio(1); 16 MFMA; setprio(0); vmcnt(N); barrier}.
// Counted-vmcnt ladder (derived for this issue order, never 0 in loop):
//   issue: ph0: B rounds 0,1 | ph1: B rounds 2,3 | ph2: A rounds 0,1 | ph3: A rounds 2,3
//   consume (tile t+1): ph0 needs all B + A-round0; ph q needs A-round q
//   waits: end ph0 -> vmcnt(4), ph1 -> 5, ph2 -> 6, ph3 -> 3   (>=2 phases of cover)
__device__ __forceinline__ void gld16(void* lds, const void* g) {
    __builtin_amdgcn_global_load_lds(
        (const __attribute__((address_space(1))) unsigned int*)g,
        (__attribute__((address_space(3))) unsigned int*)lds,
        16, 0, 0);
}

__device__ __forceinline__ short8 rd8(const void* p) {
    return *(const short8*)p;
}

#define MFMA16 __builtin_amdgcn_mfma_f32_16x16x32_bf16

#define MM16(I0, A00, A01, A10, A11)                                      \
    do {                                                                  \
        _Pragma("unroll")                                                 \
        for (int j = 0; j < 4; ++j) {                                     \
            acc[I0][j]     = MFMA16(A00, b[j][0], acc[I0][j],     0,0,0); \
            acc[I0][j]     = MFMA16(A01, b[j][1], acc[I0][j],     0,0,0); \
            acc[(I0)+1][j] = MFMA16(A10, b[j][0], acc[(I0)+1][j], 0,0,0); \
            acc[(I0)+1][j] = MFMA16(A11, b[j][1], acc[(I0)+1][j], 0,0,0); \
        }                                                                 \
    } while (0)

#define PHASE(Q, S1, S2, VM)                                              \
    do {                                                                  \
        short8 aa0 = rd8(LA + rA + (2*(Q))*2048   + cA0);                 \
        short8 aa1 = rd8(LA + rA + (2*(Q))*2048   + (cA0^64));            \
        short8 aa2 = rd8(LA + rA + (2*(Q)+1)*2048 + cA0);                 \
        short8 aa3 = rd8(LA + rA + (2*(Q)+1)*2048 + (cA0^64));            \
        S1; S2;                                                           \
        __builtin_amdgcn_s_barrier();                                     \
        asm volatile("s_waitcnt lgkmcnt(0)" ::: "memory");                \
        __builtin_amdgcn_sched_barrier(0);                                \
        __builtin_amdgcn_s_setprio(1);                                    \
        MM16(2*(Q), aa0, aa1, aa2, aa3);                                  \
        __builtin_amdgcn_s_setprio(0);                                    \
        asm volatile("s_waitcnt " VM ::: "memory");                       \
        __builtin_amdgcn_s_barrier();                                     \
    } while (0)

__global__ __launch_bounds__(512) void conv_kernel(const unsigned short* __restrict__ qw,
                                                   const unsigned short* __restrict__ qx,
                                                   float* __restrict__ out) {
    __shared__ unsigned short lds[65536];     // 128 KiB: [A0|B0|A1|B1], 32 KiB each
    char* Lc = (char*)lds;

    const int tid  = threadIdx.x;
    const int w    = tid >> 6;
    const int lane = tid & 63;
    const int lo16 = lane & 15;
    const int quad = lane >> 4;
    const int wm   = w & 1;                   // 2 waves in M
    const int wn   = w >> 1;                  // 4 waves in N

    // XCD swizzle: blocks with id%8==x land on XCD x (round-robin dispatch);
    // each XCD works images {x, x+8, x+16, x+24} -> qx panels stay L2-local.
    const int id  = blockIdx.x;               // 0..511
    const int idx = id >> 3;                  // 0..63
    const int n   = (id & 7) + ((idx >> 4) << 3);
    const int pt  = idx & 15;                 // pixel tile within image
    const int h0  = pt * 4;
    const int hw0 = pt * 256;

    // ---- staging (write-side) precompute: linear LDS dest, inverse-swizzled src ----
    const int trow  = tid >> 3;                              // 0..63 (8 lanes per row)
    const int c_off = ((tid & 7) ^ (trow & 7)) << 3;         // swizzled source col (elems)
    const unsigned short* gB = qx + ((size_t)((n*HP + h0 + 1) * WP + trow + 1)) * C_IN + c_off;
    const int ro0 = trow + ((tid >= 256) ? 96 : 0);          // A quadrant-major row map
    const unsigned short* gA = qw + (size_t)ro0 * C_IN + c_off;
    const int awb = w * 1024 + ((w < 4) ? 0 : 12288);        // A stage lds byte base (+q*4096)
    const int bwb = w * 1024;                                // B stage lds byte base (+j*8192)

    // ---- read-side precompute (same XOR) ----
    const int key = (lo16 & 7) << 4;
    const int cA0 = (quad << 4) ^ key;                       // ks=0 col byte; ks=1 = cA0^64
    const int rA  = (wm * 128 + lo16) * 128;                 // + i*2048
    const int rB  = (wn * 64  + lo16) * 128;                 // + j*2048

    f32x4 acc[8][4];
#pragma unroll
    for (int i = 0; i < 8; ++i)
#pragma unroll
        for (int j = 0; j < 4; ++j)
            acc[i][j] = (f32x4){0.f, 0.f, 0.f, 0.f};

    // ---- prologue: stage K-tile 0 (p=0: dh=-1,dw=-1, c0=0) into buf0, full drain ----
    {
        const unsigned short* ga = gA;
        const unsigned short* gb = gB - 17152;               // (-66-1)*256
        char* SA = Lc;
        char* SB = Lc + 32768;
        gld16(SB + bwb,         gb);
        gld16(SB + bwb + 8192,  gb + 16896);
        gld16(SB + bwb + 16384, gb + 2*16896);
        gld16(SB + bwb + 24576, gb + 3*16896);
        gld16(SA + awb,         ga);
        gld16(SA + awb + 4096,  ga + 8192);
        gld16(SA + awb + 8192,  ga + 16384);
        gld16(SA + awb + 12288, ga + 24576);
        asm volatile("s_waitcnt vmcnt(0)" ::: "memory");
        __builtin_amdgcn_s_barrier();
    }

    int curOff = 0;
#pragma unroll 1
    for (int t = 0; t < 36; ++t) {
        // next tile to stage (t=35 harmlessly re-stages 35 to keep vmcnt counts exact)
        const int tn  = (t < 35) ? (t + 1) : 35;
        const int pn  = tn >> 2;
        const int qn  = pn / 3;
        const int dwn = pn - qn * 3;
        const int cn  = (tn & 3) << 6;
        const unsigned short* ga = gA + pn * 65536 + cn;
        const unsigned short* gb = gB + (ptrdiff_t)((qn - 1) * WP + (dwn - 1)) * C_IN + cn;

        const char* LA = Lc + curOff;                        // compute buffer
        const char* LB = LA + 32768;
        char* SA = Lc + (curOff ^ 65536);                    // stage buffer
        char* SB = SA + 32768;

        short8 b[4][2];
#pragma unroll
        for (int j = 0; j < 4; ++j) {
            b[j][0] = rd8(LB + rB + j*2048 + cA0);
            b[j][1] = rd8(LB + rB + j*2048 + (cA0^64));
        }

        PHASE(0, gld16(SB + bwb,         gb),
                 gld16(SB + bwb + 8192,  gb + 16896),   "vmcnt(4)");
        PHASE(1, gld16(SB + bwb + 16384, gb + 2*16896),
                 gld16(SB + bwb + 24576, gb + 3*16896), "vmcnt(5)");
        PHASE(2, gld16(SA + awb,         ga),
                 gld16(SA + awb + 4096,  ga + 8192),    "vmcnt(6)");
        PHASE(3, gld16(SA + awb + 8192,  ga + 16384),
                 gld16(SA + awb + 12288, ga + 24576),   "vmcnt(3)");

        curOff ^= 65536;
    }

    // ---- epilogue: same C/D mapping as verified 128x128 kernel ----
#pragma unroll
    for (int i = 0; i < 8; ++i) {
        const int o = wm * 128 + i * 16 + quad * 4;
        float* orow = out + ((size_t)(n * O_OUT + o)) * (HH*WW) + hw0 + wn * 64 + lo16;
#pragma unroll
        for (int j = 0; j < 4; ++j) {
            float* dst = orow + j * 16;
#pragma unroll
            for (int r = 0; r < 4; ++r)
                dst[(size_t)r * (HH*WW)] = acc[i][j][r];
        }
    }
}

extern "C" void kernel_launch(void* const* d_in, const int* in_sizes, int n_in,
                              void* d_out, int out_size, void* d_ws, size_t ws_size,
                              hipStream_t stream) {
    const float* x = (const float*)d_in[0];
    const float* w = (const float*)d_in[1];
    float* out = (float*)d_out;

    unsigned short* qx = (unsigned short*)d_ws;                       // padded NHWC bf16
    unsigned short* qw = (unsigned short*)((char*)d_ws + QX_BYTES);   // [9][O][C] bf16

    halo_zero_kernel<<<dim3(1040), 256, 0, stream>>>(qx);
    quant_x_kernel<<<dim3(N_IMG*HH*4), 256, 0, stream>>>(x, qx);
    quant_w_kernel<<<dim3(O_OUT), 256, 0, stream>>>(w, qw);
    conv_kernel<<<dim3(512), 512, 0, stream>>>(qw, qx, out);
}

// Round 3
// 350.130 us; speedup vs baseline: 1.2346x; 1.0377x over previous
//
#include <hip/hip_runtime.h>
#include <stdint.h>
#include <stddef.h>

typedef __attribute__((ext_vector_type(8))) short short8;
typedef __attribute__((ext_vector_type(4))) float f32x4;

#define N_IMG 32
#define C_IN  256
#define HH    64
#define WW    64
#define O_OUT 256
#define HP    66
#define WP    66

#define QX_ELEMS (N_IMG*HP*WP*C_IN)      // 35,684,352
#define QX_BYTES ((size_t)QX_ELEMS*2)    // 71,368,704
#define QW_ELEMS (9*O_OUT*C_IN)          // 589,824

// ---------- quantization helpers (match jnp reference bit-for-bit) ----------

// nearest E2M1 magnitude; ties round up (jnp.digitize right=False: a==mid -> upper)
__device__ __forceinline__ float e2m1_mag(float a) {
    return a < 0.25f ? 0.0f
         : a < 0.75f ? 0.5f
         : a < 1.25f ? 1.0f
         : a < 1.75f ? 1.5f
         : a < 2.5f  ? 2.0f
         : a < 3.5f  ? 3.0f
         : a < 5.0f  ? 4.0f : 6.0f;
}

// scale = 2^ceil(log2(max(amax,1e-30)/6)), or 1.0 if amax==0; also exact 1/scale.
__device__ __forceinline__ void blk_scale2(float amax, float& s, float& inv) {
    float ac = fmaxf(amax, 1e-30f);
    int e;
    float m = frexpf(ac, &e);
    int ex = (m > 0.75f) ? (e - 2) : (e - 3);
    if (amax > 0.0f) { s = ldexpf(1.0f, ex); inv = ldexpf(1.0f, -ex); }
    else             { s = 1.0f; inv = 1.0f; }
}

// E2M1-grid * pow2 -> 1 mantissa bit -> exact in bf16 (truncate == round)
__device__ __forceinline__ unsigned short to_bf16_bits(float v) {
    union { float f; unsigned int u; } cv; cv.f = v;
    return (unsigned short)(cv.u >> 16);
}

// ---------- halo zero: only the 4.3 MB border of qx (replaces 71 MB memset) ----------
__global__ __launch_bounds__(256) void halo_zero_kernel(unsigned short* __restrict__ qx) {
    int id = blockIdx.x * 256 + threadIdx.x;
    size_t off;
    if (id < 135168) {
        int n = id / 4224, r = id % 4224;
        int h = (r / 2112) * 65;
        int k = r % 2112;
        off = (((size_t)(n*HP + h)) * WP) * C_IN + (size_t)k * 8;
    } else {
        int j = id - 135168;
        int n = j >> 12, r = j & 4095;
        int h = 1 + (r >> 6);
        int w = ((r >> 5) & 1) * 65;
        int k = r & 31;
        off = (((size_t)(n*HP + h)) * WP + w) * C_IN + (size_t)k * 8;
    }
    uint4 z; z.x = z.y = z.z = z.w = 0u;
    *(uint4*)(qx + off) = z;
}

// ---------- x: fp32 NCHW -> exact-bf16 NHWC(+halo) ----------
__global__ __launch_bounds__(256) void quant_x_kernel(const float* __restrict__ x,
                                                      unsigned short* __restrict__ qx) {
    __shared__ float xf[64][65];     // [c_local][w], pad 1 -> transpose reads 2-way
    __shared__ float sarr[4][65];    // [wb][c_local] scale
    __shared__ float iarr[4][65];    // [wb][c_local] 1/scale (exact pow2)

    const int bid = blockIdx.x;
    const int n  = bid >> 8;
    const int h  = (bid >> 2) & 63;
    const int cb = bid & 3;
    const int t  = threadIdx.x;

    {
        const int rb = t >> 4;            // 0..15
        const int w4 = (t & 15) * 4;
        const float* src = x + (((size_t)(n*C_IN + cb*64)) * HH + h) * WW;
#pragma unroll
        for (int it = 0; it < 4; ++it) {
            int r = it * 16 + rb;
            float4 g = *(const float4*)(src + (size_t)r * (HH*WW) + w4);
            xf[r][w4+0] = g.x; xf[r][w4+1] = g.y; xf[r][w4+2] = g.z; xf[r][w4+3] = g.w;
        }
    }
    __syncthreads();

    {
        const int c = t >> 2, wb = t & 3;
        float amax = 0.f;
#pragma unroll
        for (int j = 0; j < 16; ++j) amax = fmaxf(amax, fabsf(xf[c][wb*16 + j]));
        float s, inv;
        blk_scale2(amax, s, inv);
        sarr[wb][c] = s;
        iarr[wb][c] = inv;
    }
    __syncthreads();

    {
        const int w = t >> 2, cg = (t & 3) * 16, wb = w >> 4;
        unsigned short outv[16];
#pragma unroll
        for (int i = 0; i < 16; ++i) {
            int c = cg + i;
            float v = xf[c][w];
            float q = copysignf(e2m1_mag(fabsf(v) * iarr[wb][c]) * sarr[wb][c], v);
            outv[i] = to_bf16_bits(q);
        }
        unsigned short* dst = qx + (((size_t)(n*HP + h + 1)) * WP + (w + 1)) * C_IN + cb*64 + cg;
        *(uint4*)(dst)     = *(const uint4*)&outv[0];
        *(uint4*)(dst + 8) = *(const uint4*)&outv[8];
    }
}

// ---------- w: fp32 OIHW -> exact-bf16 [kpos][O][C], one block per o ----------
__global__ __launch_bounds__(256) void quant_w_kernel(const float* __restrict__ w,
                                                      unsigned short* __restrict__ qw) {
    __shared__ unsigned short lq[2304];   // one o-row, flat (ci*9 + p) order
    const int o = blockIdx.x;
    const int t = threadIdx.x;
    const float* src = w + (size_t)o * 2304;
    if (t < 144) {                        // 144 quant blocks of 16 per o
        float v[16];
#pragma unroll
        for (int j = 0; j < 4; ++j) {
            float4 f = ((const float4*)(src + t*16))[j];
            v[j*4+0]=f.x; v[j*4+1]=f.y; v[j*4+2]=f.z; v[j*4+3]=f.w;
        }
        float amax = 0.f;
#pragma unroll
        for (int j = 0; j < 16; ++j) amax = fmaxf(amax, fabsf(v[j]));
        float s, inv;
        blk_scale2(amax, s, inv);
#pragma unroll
        for (int j = 0; j < 16; ++j)
            lq[t*16 + j] = to_bf16_bits(copysignf(e2m1_mag(fabsf(v[j]) * inv) * s, v[j]));
    }
    __syncthreads();
#pragma unroll
    for (int p = 0; p < 9; ++p)
        qw[((size_t)(p*O_OUT + o)) * C_IN + t] = lq[t*9 + p];
}

// ---------- conv: implicit GEMM, 256x256 tile, BK=64, 4-phase, in-region ds_reads ----------
// A = weights [O=256][K], B = pixels [256][K]; K = 9 taps x 256 ch = 36 K-tiles of 64.
// 8 waves (2M x 4N). LDS 128 KiB = 2 dbuf x (A 32K + B 32K). T2 XOR-swizzle.
//
// All fragment ds_reads are issued inside the PREVIOUS phase's MFMA region (LDS port
// overlaps the matrix pipe); every lgkm wait is a true lgkmcnt(0) with >=1 MFMA region
// of slack. vmcnt ladder proves staged data ready BEFORE the in-region ds_read issues:
//   issues/tile: PH0:{Br0,Br1} PH1:{Br2,Br3} PH2:{Ar0,Ar1} PH3:{Ar2,Ar3}
//   waits:  PH0 vmcnt(3) -> drains Ar2(t)     => quad2 readable in PH1 region
//           PH1 vmcnt(4) -> drains Ar3(t)     => quad3 readable in PH2 region
//           PH2 vmcnt(2) -> drains Br0..3(t+1) => B(t+1) readable in PH3 region
//           PH3 vmcnt(2) -> drains Ar0/1(t+1)  => quad0/1(t+1) readable at tile top
// v4 fix (v3 was WRONG): B(t+1) read in PH3 must NOT overwrite the live B(t) regs
// consumed by PH3's own MFMAs. B fragments are register-double-buffered (b0/b1,
// static names per rule-20) via a 2-tile-unrolled loop; buffer offsets become
// compile-time constants.
__device__ __forceinline__ void gld16(void* lds, const void* g) {
    __builtin_amdgcn_global_load_lds(
        (const __attribute__((address_space(1))) unsigned int*)g,
        (__attribute__((address_space(3))) unsigned int*)lds,
        16, 0, 0);
}

__device__ __forceinline__ short8 rd8(const void* p) {
    return *(const short8*)p;
}

#define MFMA16 __builtin_amdgcn_mfma_f32_16x16x32_bf16

// accumulate quadrant I0 (rows) x all 4 b-columns; k-slice order 0 then 1 (bit-exact)
#define MM16(I0, A00, A01, A10, A11, B)                                   \
    do {                                                                  \
        _Pragma("unroll")                                                 \
        for (int j = 0; j < 4; ++j) {                                     \
            acc[I0][j]     = MFMA16(A00, B[j][0], acc[I0][j],     0,0,0); \
            acc[I0][j]     = MFMA16(A01, B[j][1], acc[I0][j],     0,0,0); \
            acc[(I0)+1][j] = MFMA16(A10, B[j][0], acc[(I0)+1][j], 0,0,0); \
            acc[(I0)+1][j] = MFMA16(A11, B[j][1], acc[(I0)+1][j], 0,0,0); \
        }                                                                 \
    } while (0)

// load A-quadrant Q into 4 named regs (from compute buffer LA)
#define RDQ(D0, D1, D2, D3, Q)                                            \
    D0 = rd8(LA + rA + (2*(Q))*2048   + cA0);                             \
    D1 = rd8(LA + rA + (2*(Q))*2048   + (cA0^64));                        \
    D2 = rd8(LA + rA + (2*(Q)+1)*2048 + cA0);                             \
    D3 = rd8(LA + rA + (2*(Q)+1)*2048 + (cA0^64));

#define PH_OPEN()                                                         \
    __builtin_amdgcn_s_barrier();                                         \
    asm volatile("s_waitcnt lgkmcnt(0)" ::: "memory");                    \
    __builtin_amdgcn_sched_barrier(0);                                    \
    __builtin_amdgcn_s_setprio(1);

#define PH_CLOSE(VM)                                                      \
    __builtin_amdgcn_s_setprio(0);                                        \
    asm volatile("s_waitcnt " VM ::: "memory");                           \
    __builtin_amdgcn_s_barrier();

// one K-tile: compute from buffer at LAOFF, stage tile TN into LAOFF^65536.
// BCUR = B fragments of this tile (consumed); BNXT = B fragments of next (filled PH3).
#define CONV_TILE(TN, LAOFF, BCUR, BNXT)                                  \
    do {                                                                  \
        const int tn  = (TN);                                             \
        const int pn  = tn >> 2;                                          \
        const int qn  = pn / 3;                                           \
        const int dwn = pn - qn * 3;                                      \
        const int cn  = (tn & 3) << 6;                                    \
        const unsigned short* ga = gA + pn * 65536 + cn;                  \
        const unsigned short* gb = gB + (ptrdiff_t)((qn - 1) * WP + (dwn - 1)) * C_IN + cn; \
        const char* LA = Lc + (LAOFF);                                    \
        char* SA = Lc + ((LAOFF) ^ 65536);                                \
        char* SB = SA + 32768;                                            \
        short8 aA0, aA1, aA2, aA3, aB0, aB1, aB2, aB3;                    \
        /* tile-top: quad0 (proven staged by prev PH3 vmcnt(2)+barrier) */\
        RDQ(aA0, aA1, aA2, aA3, 0);                                       \
        /* PH0: compute quad0 x BCUR; in-region read quad1 */             \
        gld16(SB + bwb,        gb);                                       \
        gld16(SB + bwb + 8192, gb + 16896);                               \
        PH_OPEN();                                                        \
        RDQ(aB0, aB1, aB2, aB3, 1);                                       \
        MM16(0, aA0, aA1, aA2, aA3, BCUR);                                \
        PH_CLOSE("vmcnt(3)");                                             \
        /* PH1: compute quad1; in-region read quad2 */                    \
        gld16(SB + bwb + 16384, gb + 2*16896);                            \
        gld16(SB + bwb + 24576, gb + 3*16896);                            \
        PH_OPEN();                                                        \
        RDQ(aA0, aA1, aA2, aA3, 2);                                       \
        MM16(2, aB0, aB1, aB2, aB3, BCUR);                                \
        PH_CLOSE("vmcnt(4)");                                             \
        /* PH2: compute quad2; in-region read quad3 */                    \
        gld16(SA + awb,        ga);                                       \
        gld16(SA + awb + 4096, ga + 8192);                                \
        PH_OPEN();                                                        \
        RDQ(aB0, aB1, aB2, aB3, 3);                                       \
        MM16(4, aA0, aA1, aA2, aA3, BCUR);                                \
        PH_CLOSE("vmcnt(2)");                                             \
        /* PH3: compute quad3 x BCUR; in-region read B(t+1) into BNXT */  \
        gld16(SA + awb + 8192,  ga + 16384);                              \
        gld16(SA + awb + 12288, ga + 24576);                              \
        PH_OPEN();                                                        \
        _Pragma("unroll")                                                 \
        for (int j = 0; j < 4; ++j) {                                     \
            BNXT[j][0] = rd8(SB + rB + j*2048 + cA0);                     \
            BNXT[j][1] = rd8(SB + rB + j*2048 + (cA0^64));                \
        }                                                                 \
        MM16(6, aB0, aB1, aB2, aB3, BCUR);                                \
        PH_CLOSE("vmcnt(2)");                                             \
    } while (0)

__global__ __launch_bounds__(512) void conv_kernel(const unsigned short* __restrict__ qw,
                                                   const unsigned short* __restrict__ qx,
                                                   float* __restrict__ out) {
    __shared__ unsigned short lds[65536];     // 128 KiB: [A0|B0|A1|B1], 32 KiB each
    char* Lc = (char*)lds;

    const int tid  = threadIdx.x;
    const int w    = tid >> 6;
    const int lane = tid & 63;
    const int lo16 = lane & 15;
    const int quad = lane >> 4;
    const int wm   = w & 1;                   // 2 waves in M
    const int wn   = w >> 1;                  // 4 waves in N

    // XCD swizzle: blocks with id%8==x land on XCD x (round-robin dispatch)
    const int id  = blockIdx.x;               // 0..511
    const int idx = id >> 3;                  // 0..63
    const int n   = (id & 7) + ((idx >> 4) << 3);
    const int pt  = idx & 15;                 // pixel tile within image
    const int h0  = pt * 4;
    const int hw0 = pt * 256;

    // ---- staging (write-side) precompute: linear LDS dest, inverse-swizzled src ----
    const int trow  = tid >> 3;                              // 0..63 (8 lanes per row)
    const int c_off = ((tid & 7) ^ (trow & 7)) << 3;         // swizzled source col (elems)
    const unsigned short* gB = qx + ((size_t)((n*HP + h0 + 1) * WP + trow + 1)) * C_IN + c_off;
    const int ro0 = trow + ((tid >= 256) ? 96 : 0);          // A quadrant-major row map
    const unsigned short* gA = qw + (size_t)ro0 * C_IN + c_off;
    const int awb = w * 1024 + ((w < 4) ? 0 : 12288);        // A stage lds byte base
    const int bwb = w * 1024;                                // B stage lds byte base

    // ---- read-side precompute (same XOR) ----
    const int key = (lo16 & 7) << 4;
    const int cA0 = (quad << 4) ^ key;                       // ks=0 col byte; ks=1 = cA0^64
    const int rA  = (wm * 128 + lo16) * 128;                 // + i*2048
    const int rB  = (wn * 64  + lo16) * 128;                 // + j*2048

    f32x4 acc[8][4];
#pragma unroll
    for (int i = 0; i < 8; ++i)
#pragma unroll
        for (int j = 0; j < 4; ++j)
            acc[i][j] = (f32x4){0.f, 0.f, 0.f, 0.f};

    // ---- prologue: stage K-tile 0 (p=0: dh=-1,dw=-1, c0=0) into buf0, full drain ----
    {
        const unsigned short* ga = gA;
        const unsigned short* gb = gB - 17152;               // (-66-1)*256
        char* SA = Lc;
        char* SB = Lc + 32768;
        gld16(SB + bwb,         gb);
        gld16(SB + bwb + 8192,  gb + 16896);
        gld16(SB + bwb + 16384, gb + 2*16896);
        gld16(SB + bwb + 24576, gb + 3*16896);
        gld16(SA + awb,         ga);
        gld16(SA + awb + 4096,  ga + 8192);
        gld16(SA + awb + 8192,  ga + 16384);
        gld16(SA + awb + 12288, ga + 24576);
        asm volatile("s_waitcnt vmcnt(0)" ::: "memory");
        __builtin_amdgcn_s_barrier();
    }

    // preload B(t=0) fragments from buf0
    short8 b0[4][2], b1[4][2];
    {
        const char* LB = Lc + 32768;
#pragma unroll
        for (int j = 0; j < 4; ++j) {
            b0[j][0] = rd8(LB + rB + j*2048 + cA0);
            b0[j][1] = rd8(LB + rB + j*2048 + (cA0^64));
        }
    }

#pragma unroll 1
    for (int tt = 0; tt < 18; ++tt) {
        const int t0 = tt * 2;
        // even tile: compute buf0, stage (t0+1) into buf1; consume b0, fill b1
        CONV_TILE(t0 + 1, 0, b0, b1);
        // odd tile: compute buf1, stage (t0+2, clamped) into buf0; consume b1, fill b0
        CONV_TILE((t0 + 2 < 36) ? (t0 + 2) : 35, 65536, b1, b0);
    }

    // drain the 2 leftover stage loads before epilogue (LDS writes in flight)
    asm volatile("s_waitcnt vmcnt(0)" ::: "memory");

    // ---- epilogue: same C/D mapping as verified kernel ----
#pragma unroll
    for (int i = 0; i < 8; ++i) {
        const int o = wm * 128 + i * 16 + quad * 4;
        float* orow = out + ((size_t)(n * O_OUT + o)) * (HH*WW) + hw0 + wn * 64 + lo16;
#pragma unroll
        for (int j = 0; j < 4; ++j) {
            float* dst = orow + j * 16;
#pragma unroll
            for (int r = 0; r < 4; ++r)
                dst[(size_t)r * (HH*WW)] = acc[i][j][r];
        }
    }
}

extern "C" void kernel_launch(void* const* d_in, const int* in_sizes, int n_in,
                              void* d_out, int out_size, void* d_ws, size_t ws_size,
                              hipStream_t stream) {
    const float* x = (const float*)d_in[0];
    const float* w = (const float*)d_in[1];
    float* out = (float*)d_out;

    unsigned short* qx = (unsigned short*)d_ws;                       // padded NHWC bf16
    unsigned short* qw = (unsigned short*)((char*)d_ws + QX_BYTES);   // [9][O][C] bf16

    halo_zero_kernel<<<dim3(1040), 256, 0, stream>>>(qx);
    quant_x_kernel<<<dim3(N_IMG*HH*4), 256, 0, stream>>>(x, qx);
    quant_w_kernel<<<dim3(O_OUT), 256, 0, stream>>>(w, qw);
    conv_kernel<<<dim3(512), 512, 0, stream>>>(qw, qx, out);
}